// Round 1
// 151.109 us; speedup vs baseline: 1.1025x; 1.1025x over previous
//
#include <hip/hip_runtime.h>
#include <hip/hip_bf16.h>
#include <stdint.h>

typedef unsigned int u32;
typedef _Float16 f16x8 __attribute__((ext_vector_type(8)));
typedef float f32x4 __attribute__((ext_vector_type(4)));

#define IJ 16384
#define NQ 1024
#define NB 2
#define KP 256
#define NSEG 8
#define SEGW 2048  // IJ / NSEG

// ---------------- Threefry-2x32 (JAX-compatible, 20 rounds) ----------------
__device__ __forceinline__ void tf2x32(u32 k0, u32 k1, u32& x0, u32& x1) {
  u32 kx = k0 ^ k1 ^ 0x1BD11BDAu;
#define TFR(r) { x0 += x1; x1 = (x1 << (r)) | (x1 >> (32 - (r))); x1 ^= x0; }
  x0 += k0; x1 += k1;
  TFR(13) TFR(15) TFR(26) TFR(6)
  x0 += k1; x1 += kx + 1u;
  TFR(17) TFR(29) TFR(16) TFR(24)
  x0 += kx; x1 += k0 + 2u;
  TFR(13) TFR(15) TFR(26) TFR(6)
  x0 += k0; x1 += k1 + 3u;
  TFR(17) TFR(29) TFR(16) TFR(24)
  x0 += k1; x1 += kx + 4u;
  TFR(13) TFR(15) TFR(26) TFR(6)
  x0 += kx; x1 += k0 + 5u;
#undef TFR
}

__device__ __forceinline__ void tf_subkey(u32 k0, u32 k1, u32 i, u32& s0, u32& s1) {
  u32 x0 = 0u, x1 = i;
  tf2x32(k0, k1, x0, x1);
  s0 = x0; s1 = x1;
}

__device__ __forceinline__ u32 tf_xorbits(u32 k0, u32 k1, u32 i) {
  u32 x0 = 0u, x1 = i;
  tf2x32(k0, k1, x0, x1);
  return x0 ^ x1;
}

__device__ __forceinline__ void derive_keys(int seed, u32& kq0, u32& kq1,
                                            u32& km0, u32& km1) {
  u32 k0 = 0u;
  u32 k1 = (u32)seed;
  tf_subkey(k0, k1, 0u, kq0, kq1);
  tf_subkey(k0, k1, 1u, km0, km1);
}

__device__ __forceinline__ float gumbel_from_bits(u32 w) {
  const float tiny = 1.17549435e-38f;
  float fl = __uint_as_float((w >> 9) | 0x3f800000u) - 1.0f;
  float u = fl * (1.0f - tiny) + tiny;
  u = fmaxf(tiny, u);
  return -logf(-logf(u));
}

__device__ __forceinline__ bool read_bool(const void* p, int idx, int is32) {
  return is32 ? (((const int*)p)[idx] != 0)
              : (((const unsigned char*)p)[idx] != 0);
}

// ---------------- setup: n_idx, bool-width detect, num_valid, zero row_max -
__global__ void setup_kernel(const void* __restrict__ valid_q,
                             const int* __restrict__ seedp,
                             float* __restrict__ row_max,
                             float* __restrict__ num_valid,
                             int* __restrict__ n_idx,
                             int* __restrict__ bool_is32) {
  __shared__ int sred[256];
  __shared__ int is32_s;
  const int blk = blockIdx.x, tid = threadIdx.x;
  if (blk < 4) {
    int s = blk * 256 + tid;  // 0..1023
    u32 kq0, kq1, km0, km1;
    derive_keys(seedp[0], kq0, kq1, km0, km1);
    u32 l0, l1;  // k2 = enc(kq, (0,1))
    tf_subkey(kq0, kq1, 1u, l0, l1);
    u32 w = tf_xorbits(l0, l1, (u32)s);
    n_idx[s] = (int)(w & 1023u);
  } else if (blk == 4) {
    const unsigned char* vb = (const unsigned char*)valid_q;
    int ones = 0;
    for (int i = tid; i < 2048; i += 256) ones += (vb[i] == 1) ? 1 : 0;
    sred[tid] = ones;
    __syncthreads();
    for (int off = 128; off > 0; off >>= 1) {
      if (tid < off) sred[tid] += sred[tid + off];
      __syncthreads();
    }
    if (tid == 0) {
      is32_s = (sred[0] < 1152) ? 1 : 0;
      bool_is32[0] = is32_s;
    }
    __syncthreads();
    const int is32 = is32_s;
    for (int b = 0; b < 2; ++b) {
      int acc = 0;
      for (int i = tid; i < NQ; i += 256)
        acc += read_bool(valid_q, b * NQ + i, is32) ? 1 : 0;
      sred[tid] = acc;
      __syncthreads();
      for (int off = 128; off > 0; off >>= 1) {
        if (tid < off) sred[tid] += sred[tid + off];
        __syncthreads();
      }
      if (tid == 0) {
        float nv = (float)sred[0];
        num_valid[b] = nv < 1.f ? 1.f : nv;
      }
      __syncthreads();
    }
  } else {
    for (int i = (blk - 5) * 256 + tid; i < NB * NQ; i += 768) row_max[i] = 0.f;
  }
}

// ---------------- GEMM via MFMA: fp32 emulated by 2-term f16 split ---------
// a = a1 + 2^-11 * a2  with a1 = f16(a), a2 = f16((a-a1)*2^11)  (a2 stays in
// f16 normal range -> no denorm hazard). Per 16x16 tile, Horner over 4 MFMAs:
//   x = m2*q2 ; x *= 2^-11 ; x += m2*q1 + m1*q2 ; x *= 2^-11 ; x += m1*q1
// -> error ~2^-21 per product, fp32-class (no sampling flips downstream).
// Fragment maps (gfx950 16x16x32): A row = l&15, B col = l&15,
// k(e) = 4*(l>>4)+e for e<4, 16+4*(l>>4)+(e-4) for e>=4;
// C/D: col = l&15, row = 4*(l>>4)+reg.
// M-dim = ij (f_map), N-dim = n (f_q): each lane's C float4 = 4 contiguous ij
// -> coalesced float4 stores of sim; row stats reduce over lanes l^16, l^32.
__global__ __launch_bounds__(256) void gemm_kernel(
    const float* __restrict__ f_q, const float* __restrict__ f_map,
    const float* __restrict__ temp, float* __restrict__ sim,
    float* __restrict__ row_max, float* __restrict__ rowsum_part) {
  __shared__ __align__(16) _Float16 ldsA[2][4][64][8];   // terms x n-tiles: 8 KB
  __shared__ __align__(16) _Float16 ldsB[2][16][64][8];  // terms x ij-tiles: 32 KB
  const int tid = threadIdx.x;
  const int b = blockIdx.z;
  const int n0 = blockIdx.y * 64;
  const int ij0 = blockIdx.x * 256;

  {  // stage A (f_q, 64 rows x 32 k) in fragment order, split
    const int l = tid & 63, rt = tid >> 6;
    const int g = l >> 4, r = l & 15;
    const float* src = f_q + ((size_t)b * NQ + n0 + rt * 16 + r) * 32 + g * 4;
    float4 v0 = *(const float4*)src;         // k = 4g..4g+3
    float4 v1 = *(const float4*)(src + 16);  // k = 16+4g..19+4g
    float x[8] = {v0.x, v0.y, v0.z, v0.w, v1.x, v1.y, v1.z, v1.w};
    f16x8 h1, h2;
#pragma unroll
    for (int e = 0; e < 8; ++e) {
      _Float16 a = (_Float16)x[e];
      h1[e] = a;
      h2[e] = (_Float16)((x[e] - (float)a) * 2048.0f);
    }
    *(f16x8*)(&ldsA[0][rt][l][0]) = h1;
    *(f16x8*)(&ldsA[1][rt][l][0]) = h2;
  }
  for (int s = tid; s < 1024; s += 256) {  // stage B (f_map, 256 cols x 32 k)
    const int l = s & 63, t = s >> 6;
    const int g = l >> 4, r = l & 15;
    const float* src = f_map + ((size_t)b * IJ + ij0 + t * 16 + r) * 32 + g * 4;
    float4 v0 = *(const float4*)src;
    float4 v1 = *(const float4*)(src + 16);
    float x[8] = {v0.x, v0.y, v0.z, v0.w, v1.x, v1.y, v1.z, v1.w};
    f16x8 h1, h2;
#pragma unroll
    for (int e = 0; e < 8; ++e) {
      _Float16 a = (_Float16)x[e];
      h1[e] = a;
      h2[e] = (_Float16)((x[e] - (float)a) * 2048.0f);
    }
    *(f16x8*)(&ldsB[0][t][l][0]) = h1;
    *(f16x8*)(&ldsB[1][t][l][0]) = h2;
  }
  __syncthreads();

  const int w = tid >> 6, l = tid & 63;
  const f16x8 q1 = *(const f16x8*)(&ldsA[0][w][l][0]);
  const f16x8 q2 = *(const f16x8*)(&ldsA[1][w][l][0]);
  const f32x4 zero4 = {0.f, 0.f, 0.f, 0.f};
  const float c11 = 4.8828125e-4f;  // 2^-11
  f32x4 acc[16];
#pragma unroll
  for (int t = 0; t < 16; ++t) {
    f16x8 m1 = *(const f16x8*)(&ldsB[0][t][l][0]);
    f16x8 m2 = *(const f16x8*)(&ldsB[1][t][l][0]);
    f32x4 x = __builtin_amdgcn_mfma_f32_16x16x32_f16(m2, q2, zero4, 0, 0, 0);
    x *= c11;
    x = __builtin_amdgcn_mfma_f32_16x16x32_f16(m2, q1, x, 0, 0, 0);
    x = __builtin_amdgcn_mfma_f32_16x16x32_f16(m1, q2, x, 0, 0, 0);
    x *= c11;
    acc[t] = __builtin_amdgcn_mfma_f32_16x16x32_f16(m1, q1, x, 0, 0, 0);
  }

  // epilogue: relu * e^temp, coalesced float4 stores, fused row max / sum-exp
  const float et = expf(temp[0]);
  const int r15 = l & 15, g = l >> 4;
  const int row = n0 + w * 16 + r15;
  float* base = sim + ((size_t)b * NQ + row) * IJ + ij0 + g * 4;
  float rm = 0.f, se = 0.f;
#pragma unroll
  for (int t = 0; t < 16; ++t) {
    float4 o;
    o.x = fmaxf(acc[t][0], 0.f) * et;
    o.y = fmaxf(acc[t][1], 0.f) * et;
    o.z = fmaxf(acc[t][2], 0.f) * et;
    o.w = fmaxf(acc[t][3], 0.f) * et;
    *(float4*)(base + t * 16) = o;
    rm = fmaxf(rm, fmaxf(fmaxf(o.x, o.y), fmaxf(o.z, o.w)));
    se += expf(o.x); se += expf(o.y); se += expf(o.z); se += expf(o.w);
  }
  // deterministic reduce over the 4 lanes (g = 0..3) holding the same row
#pragma unroll
  for (int off = 16; off < 64; off <<= 1) {
    se += __shfl_xor(se, off, 64);
    rm = fmaxf(rm, __shfl_xor(rm, off, 64));
  }
  if (g == 0) {
    rowsum_part[((size_t)(b * NQ + row)) * 64 + blockIdx.x] = se;
    atomicMax((u32*)&row_max[(size_t)b * NQ + row], __float_as_uint(rm));
  }
}

// ---------------- row_sumexp[row] = (Σ_tiles rowsum_part) * e^(-m) ---------
__global__ void sumexp_reduce_kernel(const float* __restrict__ rowsum_part,
                                     const float* __restrict__ row_max,
                                     float* __restrict__ row_sumexp) {
  const int row = blockIdx.x * 256 + threadIdx.x;  // 0..2047
  if (row >= NB * NQ) return;
  const float* p = rowsum_part + (size_t)row * 64;
  float s = 0.f;
#pragma unroll
  for (int t = 0; t < 64; ++t) s += p[t];  // fixed order: deterministic
  row_sumexp[row] = s * expf(-row_max[row]);
}

// ---------------- categorical, segmented + LDS candidate compaction --------
__global__ __launch_bounds__(256) void cat_seg_kernel(
    const float* __restrict__ sim, const float* __restrict__ row_max,
    const float* __restrict__ row_sumexp, const float* __restrict__ num_valid,
    const int* __restrict__ n_idx, const int* __restrict__ seedp,
    float* __restrict__ segv, int* __restrict__ segi) {
  __shared__ unsigned short cand[2][SEGW];
  __shared__ int ccount[2];
  __shared__ u32 keys[2];
  __shared__ float sv[2][256];
  __shared__ int si[2][256];
  const int seg = blockIdx.x;  // 0..NSEG-1
  const int t = blockIdx.y;    // 0..511
  const int tid = threadIdx.x;
  if (tid == 0) {
    u32 kq0, kq1, km0, km1;
    derive_keys(seedp[0], kq0, kq1, km0, km1);
    keys[0] = km0; keys[1] = km1;
    ccount[0] = 0; ccount[1] = 0;
  }
  __syncthreads();

  const int nA = n_idx[t], nB = n_idx[512 + t];
  const float m0 = row_max[nA], s0 = row_sumexp[nA];
  const float m1 = row_max[NQ + nB], s1 = row_sumexp[NQ + nB];
  const float nv0 = num_valid[0], nv1 = num_valid[1];
  const float thA = m0 - 25.0f;
  const float thB = m1 - 25.0f;
  const float* r0 = sim + (size_t)nA * IJ + seg * SEGW;
  const float* r1 = sim + (size_t)(NQ + nB) * IJ + seg * SEGW;

#pragma unroll
  for (int k = 0; k < 2; ++k) {
    const int l = tid + k * 256;
    const int lf = l * 4;
    float4 va = ((const float4*)r0)[l];
    float4 vb = ((const float4*)r1)[l];
    const float ra[4] = {va.x, va.y, va.z, va.w};
    const float rb[4] = {vb.x, vb.y, vb.z, vb.w};
#pragma unroll
    for (int c = 0; c < 4; ++c) {
      if (ra[c] > thA) { int p = atomicAdd(&ccount[0], 1); cand[0][p] = (unsigned short)(lf + c); }
      if (rb[c] > thB) { int p = atomicAdd(&ccount[1], 1); cand[1][p] = (unsigned short)(lf + c); }
    }
  }
  __syncthreads();

  const u32 km0 = keys[0], km1 = keys[1];
  const int c0 = ccount[0], c1 = ccount[1];
  const int fbase = seg * SEGW;
  float bv0 = -1e30f, bv1 = -1e30f;
  int bi0 = IJ, bi1 = IJ;
  for (int c = tid; c < c0; c += 256) {
    int f = fbase + (int)cand[0][c];
    u32 w = tf_xorbits(km0, km1, (u32)(t * IJ + f));
    float g = gumbel_from_bits(w);
    float e = expf(r0[f - fbase] - m0);
    float v = logf((e / s0) / nv0 + 1e-20f) + g;
    if (v > bv0 || (v == bv0 && f < bi0)) { bv0 = v; bi0 = f; }
  }
  for (int c = tid; c < c1; c += 256) {
    int f = fbase + (int)cand[1][c];
    u32 w = tf_xorbits(km0, km1, (u32)(t * IJ + f) + 8388608u);  // +2^23
    float g = gumbel_from_bits(w);
    float e = expf(r1[f - fbase] - m1);
    float v = logf((e / s1) / nv1 + 1e-20f) + g;
    if (v > bv1 || (v == bv1 && f < bi1)) { bv1 = v; bi1 = f; }
  }
  sv[0][tid] = bv0; si[0][tid] = bi0;
  sv[1][tid] = bv1; si[1][tid] = bi1;
  __syncthreads();
  for (int off = 128; off > 0; off >>= 1) {
    if (tid < off) {
#pragma unroll
      for (int q = 0; q < 2; ++q) {
        float v2 = sv[q][tid + off];
        int i2 = si[q][tid + off];
        if (v2 > sv[q][tid] || (v2 == sv[q][tid] && i2 < si[q][tid])) {
          sv[q][tid] = v2; si[q][tid] = i2;
        }
      }
    }
    __syncthreads();
  }
  if (tid == 0) {
    segv[(0 * 512 + t) * NSEG + seg] = sv[0][0];
    segi[(0 * 512 + t) * NSEG + seg] = si[0][0];
    segv[(1 * 512 + t) * NSEG + seg] = sv[1][0];
    segi[(1 * 512 + t) * NSEG + seg] = si[1][0];
  }
}

__global__ void cat_reduce_kernel(const float* __restrict__ segv,
                                  const int* __restrict__ segi,
                                  int* __restrict__ m_flat) {
  const int idx = blockIdx.x * 256 + threadIdx.x;  // 0..1023 = b*512 + t
  if (idx >= NB * 512) return;
  float bv = -1e30f;
  int bi = IJ;
#pragma unroll
  for (int s = 0; s < NSEG; ++s) {
    float v = segv[idx * NSEG + s];
    int i = segi[idx * NSEG + s];
    if (v > bv || (v == bv && i < bi)) { bv = v; bi = i; }
  }
  m_flat[idx] = bi;
}

// ---------------- pose hypotheses (R, t) -----------------------------------
__global__ void pose_kernel(const float* __restrict__ q_xy,
                            const int* __restrict__ n_idx,
                            const int* __restrict__ m_flat,
                            float4* __restrict__ poses) {
  const int idx = blockIdx.x * 256 + threadIdx.x;  // 0..511
  if (idx >= NB * KP) return;
  const int b = idx >> 8, k = idx & 255;
  const int t0 = b * 512 + 2 * k, t1 = t0 + 1;
  const int na = n_idx[t0], nb = n_idx[t1];
  const float2 q0 = ((const float2*)q_xy)[(size_t)b * NQ + na];
  const float2 q1 = ((const float2*)q_xy)[(size_t)b * NQ + nb];
  const int ma = m_flat[t0], mb = m_flat[t1];
  const float m0x = ((float)(ma >> 7) + 0.5f) * 0.5f;
  const float m0y = ((float)(ma & 127) + 0.5f) * 0.5f;
  const float m1x = ((float)(mb >> 7) + 0.5f) * 0.5f;
  const float m1y = ((float)(mb & 127) + 0.5f) * 0.5f;
  const float dqx = q1.x - q0.x, dqy = q1.y - q0.y;
  const float dmx = m1x - m0x, dmy = m1y - m0y;
  const float theta = atan2f(dmy, dmx) - atan2f(dqy, dqx);
  const float c = cosf(theta), s = sinf(theta);
  const float tx = m0x - (c * q0.x - s * q0.y);
  const float ty = m0y - (s * q0.x + c * q0.y);
  poses[idx] = make_float4(c, s, tx, ty);
}

// ---------------- score every pose -----------------------------------------
__global__ __launch_bounds__(256) void score_kernel(
    const float* __restrict__ sim, const float* __restrict__ q_xy,
    const void* __restrict__ valid_q, const void* __restrict__ valid_map,
    const float* __restrict__ num_valid, const float4* __restrict__ poses,
    const int* __restrict__ bool_is32, float* __restrict__ out) {
  __shared__ float sred[256];
  const int idx = blockIdx.x;  // b*256 + k
  const int tid = threadIdx.x;
  const int b = idx >> 8;
  const int is32 = bool_is32[0];
  const float4 P = poses[idx];
  float acc = 0.f;
  for (int n = tid; n < NQ; n += 256) {
    float2 q = ((const float2*)q_xy)[(size_t)b * NQ + n];
    float px = P.x * q.x - P.y * q.y + P.z;
    float py = P.y * q.x + P.x * q.y + P.w;
    int ii = (int)floorf(px * 2.0f);
    int jj = (int)floorf(py * 2.0f);
    bool inb = (ii >= 0) & (ii < 128) & (jj >= 0) & (jj < 128);
    int ic = min(max(ii, 0), 127), jc = min(max(jj, 0), 127);
    int flat = (ic << 7) + jc;
    bool msk = read_bool(valid_q, b * NQ + n, is32) && inb &&
               read_bool(valid_map, b * IJ + flat, is32);
    if (msk) acc += sim[((size_t)(b * NQ + n)) * IJ + flat];
  }
  sred[tid] = acc;
  __syncthreads();
  for (int off = 128; off > 0; off >>= 1) {
    if (tid < off) sred[tid] += sred[tid + off];
    __syncthreads();
  }
  if (tid == 0) out[idx] = sred[0] / num_valid[b];
}

// ---------------------------------------------------------------------------
extern "C" void kernel_launch(void* const* d_in, const int* in_sizes, int n_in,
                              void* d_out, int out_size, void* d_ws,
                              size_t ws_size, hipStream_t stream) {
  const float* f_q = (const float*)d_in[0];
  const float* f_map = (const float*)d_in[1];
  const float* q_xy = (const float*)d_in[2];
  const float* temp = (const float*)d_in[3];
  const void* valid_q = d_in[4];
  const void* valid_map = d_in[5];
  const int* seedp = (const int*)d_in[6];
  float* out = (float*)d_out;

  char* ws = (char*)d_ws;
  const size_t SIM_BYTES = (size_t)NB * NQ * IJ * 4;  // 134217728
  float* sim = (float*)ws;
  float* row_max = (float*)(ws + SIM_BYTES);
  float* row_sumexp = (float*)(ws + SIM_BYTES + 8192);
  float* num_valid = (float*)(ws + SIM_BYTES + 16384);
  int* n_idx = (int*)(ws + SIM_BYTES + 16448);
  int* m_flat = (int*)(ws + SIM_BYTES + 20544);
  float4* poses = (float4*)(ws + SIM_BYTES + 24640);
  int* bool_is32 = (int*)(ws + SIM_BYTES + 32832);
  float* segv = (float*)(ws + SIM_BYTES + 36864);       // 32 KB
  int* segi = (int*)(ws + SIM_BYTES + 69632);           // 32 KB
  float* rowsum_part = (float*)(ws + SIM_BYTES + 102400);  // 2048*64 f32 = 512 KB

  setup_kernel<<<8, 256, 0, stream>>>(valid_q, seedp, row_max, num_valid,
                                      n_idx, bool_is32);
  gemm_kernel<<<dim3(64, 16, 2), 256, 0, stream>>>(f_q, f_map, temp, sim,
                                                   row_max, rowsum_part);
  sumexp_reduce_kernel<<<8, 256, 0, stream>>>(rowsum_part, row_max, row_sumexp);
  cat_seg_kernel<<<dim3(NSEG, 512), 256, 0, stream>>>(
      sim, row_max, row_sumexp, num_valid, n_idx, seedp, segv, segi);
  cat_reduce_kernel<<<4, 256, 0, stream>>>(segv, segi, m_flat);
  pose_kernel<<<2, 256, 0, stream>>>(q_xy, n_idx, m_flat, poses);
  score_kernel<<<NB * KP, 256, 0, stream>>>(sim, q_xy, valid_q, valid_map,
                                            num_valid, poses, bool_is32, out);
}

// Round 2
// 144.921 us; speedup vs baseline: 1.1496x; 1.0427x over previous
//
#include <hip/hip_runtime.h>
#include <stdint.h>

typedef unsigned int u32;
typedef unsigned long long u64;
typedef _Float16 f16x8 __attribute__((ext_vector_type(8)));
typedef _Float16 f16x4 __attribute__((ext_vector_type(4)));
typedef float f32x4 __attribute__((ext_vector_type(4)));

#define IJ 16384
#define NQ 1024
#define NB 2
#define KP 256
#define NSEG 16
#define SEGW 1024  // IJ / NSEG
#define NT 1024    // sampled rows (2 batches x 512)

// ---------------- Threefry-2x32 (JAX-compatible, 20 rounds) ----------------
__device__ __forceinline__ void tf2x32(u32 k0, u32 k1, u32& x0, u32& x1) {
  u32 kx = k0 ^ k1 ^ 0x1BD11BDAu;
#define TFR(r) { x0 += x1; x1 = (x1 << (r)) | (x1 >> (32 - (r))); x1 ^= x0; }
  x0 += k0; x1 += k1;
  TFR(13) TFR(15) TFR(26) TFR(6)
  x0 += k1; x1 += kx + 1u;
  TFR(17) TFR(29) TFR(16) TFR(24)
  x0 += kx; x1 += k0 + 2u;
  TFR(13) TFR(15) TFR(26) TFR(6)
  x0 += k0; x1 += k1 + 3u;
  TFR(17) TFR(29) TFR(16) TFR(24)
  x0 += k1; x1 += kx + 4u;
  TFR(13) TFR(15) TFR(26) TFR(6)
  x0 += kx; x1 += k0 + 5u;
#undef TFR
}

__device__ __forceinline__ void tf_subkey(u32 k0, u32 k1, u32 i, u32& s0, u32& s1) {
  u32 x0 = 0u, x1 = i;
  tf2x32(k0, k1, x0, x1);
  s0 = x0; s1 = x1;
}

__device__ __forceinline__ u32 tf_xorbits(u32 k0, u32 k1, u32 i) {
  u32 x0 = 0u, x1 = i;
  tf2x32(k0, k1, x0, x1);
  return x0 ^ x1;
}

__device__ __forceinline__ void derive_keys(int seed, u32& kq0, u32& kq1,
                                            u32& km0, u32& km1) {
  u32 k0 = 0u;
  u32 k1 = (u32)seed;
  tf_subkey(k0, k1, 0u, kq0, kq1);
  tf_subkey(k0, k1, 1u, km0, km1);
}

__device__ __forceinline__ float gumbel_from_bits(u32 w) {
  const float tiny = 1.17549435e-38f;
  float fl = __uint_as_float((w >> 9) | 0x3f800000u) - 1.0f;
  float u = fl * (1.0f - tiny) + tiny;
  u = fmaxf(tiny, u);
  return -logf(-logf(u));
}

__device__ __forceinline__ bool read_bool(const void* p, int idx, int is32) {
  return is32 ? (((const int*)p)[idx] != 0)
              : (((const unsigned char*)p)[idx] != 0);
}

// monotone float<->u32 key (finite, non-NaN inputs)
__device__ __forceinline__ u32 fkey(float x) {
  u32 b = __float_as_uint(x);
  return b ^ ((b & 0x80000000u) ? 0xFFFFFFFFu : 0x80000000u);
}
__device__ __forceinline__ float fkey_inv(u32 k) {
  u32 b = k ^ ((k & 0x80000000u) ? 0x80000000u : 0xFFFFFFFFu);
  return __uint_as_float(b);
}

// f32 -> (f16 hi, f16 lo*2^11) split
__device__ __forceinline__ void split8(const float* x, f16x8& h1, f16x8& h2) {
#pragma unroll
  for (int e = 0; e < 8; ++e) {
    _Float16 a = (_Float16)x[e];
    h1[e] = a;
    h2[e] = (_Float16)((x[e] - (float)a) * 2048.0f);
  }
}

// ---------------- setup: n_idx, bool detect, num_valid, tmax=0, f16 splits -
// grid 552: [0,4) n_idx, 4 bool+num_valid, [5,8) zero tmax,
//           [8,520) f_map split (4 tiles/blk), [520,552) f_q split
__global__ void setup_kernel(const void* __restrict__ valid_q,
                             const int* __restrict__ seedp,
                             const float* __restrict__ f_q,
                             const float* __restrict__ f_map,
                             float* __restrict__ tmax,
                             float* __restrict__ num_valid,
                             int* __restrict__ n_idx,
                             int* __restrict__ bool_is32,
                             _Float16* __restrict__ ms1,
                             _Float16* __restrict__ ms2,
                             _Float16* __restrict__ qs1,
                             _Float16* __restrict__ qs2) {
  __shared__ int sred[256];
  __shared__ int is32_s;
  const int blk = blockIdx.x, tid = threadIdx.x;
  if (blk < 4) {
    int s = blk * 256 + tid;  // 0..1023
    u32 kq0, kq1, km0, km1;
    derive_keys(seedp[0], kq0, kq1, km0, km1);
    u32 l0, l1;  // k2 = enc(kq, (0,1))
    tf_subkey(kq0, kq1, 1u, l0, l1);
    u32 w = tf_xorbits(l0, l1, (u32)s);
    n_idx[s] = (int)(w & 1023u);
  } else if (blk == 4) {
    const unsigned char* vb = (const unsigned char*)valid_q;
    int ones = 0;
    for (int i = tid; i < 2048; i += 256) ones += (vb[i] == 1) ? 1 : 0;
    sred[tid] = ones;
    __syncthreads();
    for (int off = 128; off > 0; off >>= 1) {
      if (tid < off) sred[tid] += sred[tid + off];
      __syncthreads();
    }
    if (tid == 0) {
      is32_s = (sred[0] < 1152) ? 1 : 0;
      bool_is32[0] = is32_s;
    }
    __syncthreads();
    const int is32 = is32_s;
    for (int b = 0; b < 2; ++b) {
      int acc = 0;
      for (int i = tid; i < NQ; i += 256)
        acc += read_bool(valid_q, b * NQ + i, is32) ? 1 : 0;
      sred[tid] = acc;
      __syncthreads();
      for (int off = 128; off > 0; off >>= 1) {
        if (tid < off) sred[tid] += sred[tid + off];
        __syncthreads();
      }
      if (tid == 0) {
        float nv = (float)sred[0];
        num_valid[b] = nv < 1.f ? 1.f : nv;
      }
      __syncthreads();
    }
  } else if (blk < 8) {
    for (int i = (blk - 5) * 256 + tid; i < NT; i += 768) tmax[i] = 0.f;
  } else if (blk < 520) {
    // f_map -> fragment-layout f16 split: tile TT, lane l holds
    // row = (TT&1023)*16 + (l&15), k(e) = 4*(l>>4)+e / 16+4*(l>>4)+(e-4)
    const int TT = (blk - 8) * 4 + (tid >> 6);  // 0..2047 (b*1024 + T)
    const int l = tid & 63;
    const int bb = TT >> 10, T = TT & 1023;
    const float* src =
        f_map + ((size_t)bb * IJ + T * 16 + (l & 15)) * 32 + ((l >> 4) << 2);
    float4 v0 = *(const float4*)src;
    float4 v1 = *(const float4*)(src + 16);
    float x[8] = {v0.x, v0.y, v0.z, v0.w, v1.x, v1.y, v1.z, v1.w};
    f16x8 h1, h2;
    split8(x, h1, h2);
    *(f16x8*)(ms1 + (size_t)(TT * 64 + l) * 8) = h1;
    *(f16x8*)(ms2 + (size_t)(TT * 64 + l) * 8) = h2;
  } else {
    // f_q -> plain [b][n][32] f16 split
    const int i = (blk - 520) * 256 + tid;  // 0..8191, 8 floats each
    const float* src = f_q + (size_t)i * 8;
    float4 a = *(const float4*)src;
    float4 b4 = *(const float4*)(src + 4);
    float x[8] = {a.x, a.y, a.z, a.w, b4.x, b4.y, b4.z, b4.w};
    f16x8 h1, h2;
    split8(x, h1, h2);
    *(f16x8*)(qs1 + (size_t)i * 8) = h1;
    *(f16x8*)(qs2 + (size_t)i * 8) = h2;
  }
}

// ---------------- per-sampled-row stats: max + partial sumexp --------------
// grid (64 ij-chunks, 16 t-tiles); wave w owns rows [by*64+16w, +16).
// sim row values recomputed bitwise-identically in select_kernel.
__global__ __launch_bounds__(256) void stats_kernel(
    const _Float16* __restrict__ ms1, const _Float16* __restrict__ ms2,
    const _Float16* __restrict__ qs1, const _Float16* __restrict__ qs2,
    const int* __restrict__ n_idx, const float* __restrict__ temp,
    float* __restrict__ tmax, float* __restrict__ rowsum_part) {
  const int bx = blockIdx.x;  // ij-chunk (256 ij)
  const int by = blockIdx.y;  // t-tile (64 rows)
  const int tid = threadIdx.x;
  const int w = tid >> 6, l = tid & 63, l15 = l & 15, g = l >> 4;
  const int b = by >> 3;
  const int tp = by * 64 + w * 16 + l15;
  const int n = n_idx[tp];
  const size_t qb = ((size_t)b * NQ + n) * 32 + g * 4;
  union { f16x8 v8; f16x4 v4[2]; } uq;
  uq.v4[0] = *(const f16x4*)(qs1 + qb);
  uq.v4[1] = *(const f16x4*)(qs1 + qb + 16);
  const f16x8 q1 = uq.v8;
  uq.v4[0] = *(const f16x4*)(qs2 + qb);
  uq.v4[1] = *(const f16x4*)(qs2 + qb + 16);
  const f16x8 q2 = uq.v8;
  const float et = expf(temp[0]);
  const f32x4 zero4 = {0.f, 0.f, 0.f, 0.f};
  const float c11 = 4.8828125e-4f;  // 2^-11
  const size_t mbase = ((size_t)b * 1024 + bx * 16) * 512 + (size_t)l * 8;
  float rm = 0.f, se = 0.f;
#pragma unroll
  for (int T = 0; T < 16; ++T) {
    const f16x8 m1 = *(const f16x8*)(ms1 + mbase + (size_t)T * 512);
    const f16x8 m2 = *(const f16x8*)(ms2 + mbase + (size_t)T * 512);
    f32x4 x = __builtin_amdgcn_mfma_f32_16x16x32_f16(m2, q2, zero4, 0, 0, 0);
    x *= c11;
    x = __builtin_amdgcn_mfma_f32_16x16x32_f16(m2, q1, x, 0, 0, 0);
    x = __builtin_amdgcn_mfma_f32_16x16x32_f16(m1, q2, x, 0, 0, 0);
    x *= c11;
    f32x4 r = __builtin_amdgcn_mfma_f32_16x16x32_f16(m1, q1, x, 0, 0, 0);
#pragma unroll
    for (int j = 0; j < 4; ++j) {
      float v = fmaxf(r[j], 0.f) * et;
      rm = fmaxf(rm, v);
      se += __expf(v);  // s only enters v as per-row log-shift: fast exp safe
    }
  }
  // deterministic reduce over the 4 lanes (g=0..3) holding the same row
  se += __shfl_xor(se, 16, 64);
  rm = fmaxf(rm, __shfl_xor(rm, 16, 64));
  se += __shfl_xor(se, 32, 64);
  rm = fmaxf(rm, __shfl_xor(rm, 32, 64));
  if (g == 0) {
    rowsum_part[(size_t)tp * 64 + bx] = se;
    atomicMax((u32*)&tmax[tp], __float_as_uint(rm));  // nonneg floats
  }
}

// ---------------- tsum[t] = (Σ_chunks rowsum_part) * e^(-m) ----------------
__global__ void sumexp_reduce_kernel(const float* __restrict__ rowsum_part,
                                     const float* __restrict__ tmax,
                                     float* __restrict__ tsum) {
  const int row = blockIdx.x * 256 + threadIdx.x;  // 0..1023
  if (row >= NT) return;
  const float* p = rowsum_part + (size_t)row * 64;
  float s = 0.f;
#pragma unroll
  for (int t = 0; t < 64; ++t) s += p[t];  // fixed order: deterministic
  tsum[row] = s * expf(-tmax[row]);
}

// ---------------- fused recompute + categorical argmax ---------------------
// Block = 16 sampled rows x SEGW ij. Recomputes sim (bitwise == stats pass),
// compacts candidates (r > m-25; winner bound r >= m-21.11) per 256-ij
// sub-chunk (structural LDS cap 4096), then dense-evals the exact R7 v and
// folds (max v, tie min f) via order-independent packed u64 atomicMax.
__global__ __launch_bounds__(256) void select_kernel(
    const _Float16* __restrict__ ms1, const _Float16* __restrict__ ms2,
    const _Float16* __restrict__ qs1, const _Float16* __restrict__ qs2,
    const int* __restrict__ n_idx, const float* __restrict__ temp,
    const float* __restrict__ tmax, const float* __restrict__ tsum,
    const float* __restrict__ num_valid, const int* __restrict__ seedp,
    float* __restrict__ segv, int* __restrict__ segi) {
  __shared__ float mrow[16], srow[16];
  __shared__ u64 best[16];
  __shared__ u32 keysm[2];
  __shared__ int cnt;
  __shared__ u32 candk[4096];
  __shared__ float candv[4096];
  const int seg = blockIdx.x;  // 0..15
  const int tg = blockIdx.y;   // 0..63
  const int tid = threadIdx.x;
  const int w = tid >> 6, l = tid & 63, l15 = l & 15, g = l >> 4;
  const int b = tg >> 5;
  const int t0 = tg * 16;
  if (tid < 16) {
    mrow[tid] = tmax[t0 + tid];
    srow[tid] = tsum[t0 + tid];
    best[tid] = ((u64)fkey(-1e30f) << 32) | (u64)(0xFFFFFFFFu - (u32)IJ);
  }
  if (tid == 0) {
    u32 kq0, kq1, km0, km1;
    derive_keys(seedp[0], kq0, kq1, km0, km1);
    keysm[0] = km0; keysm[1] = km1;
    cnt = 0;
  }
  const int tp = t0 + l15;
  const int n = n_idx[tp];
  const size_t qb = ((size_t)b * NQ + n) * 32 + g * 4;
  union { f16x8 v8; f16x4 v4[2]; } uq;
  uq.v4[0] = *(const f16x4*)(qs1 + qb);
  uq.v4[1] = *(const f16x4*)(qs1 + qb + 16);
  const f16x8 q1 = uq.v8;
  uq.v4[0] = *(const f16x4*)(qs2 + qb);
  uq.v4[1] = *(const f16x4*)(qs2 + qb + 16);
  const f16x8 q2 = uq.v8;
  const float et = expf(temp[0]);
  const f32x4 zero4 = {0.f, 0.f, 0.f, 0.f};
  const float c11 = 4.8828125e-4f;
  const float nv = num_valid[b];
  __syncthreads();
  const float th = mrow[l15] - 25.0f;
  const u32 km0 = keysm[0], km1 = keysm[1];

  for (int sc = 0; sc < 4; ++sc) {
#pragma unroll
    for (int i = 0; i < 4; ++i) {
      const int Tl = sc * 16 + w * 4 + i;  // tile within seg: 0..63
      const size_t moff = ((size_t)(b * 1024 + seg * 64 + Tl) * 64 + l) * 8;
      const f16x8 m1 = *(const f16x8*)(ms1 + moff);
      const f16x8 m2 = *(const f16x8*)(ms2 + moff);
      f32x4 x = __builtin_amdgcn_mfma_f32_16x16x32_f16(m2, q2, zero4, 0, 0, 0);
      x *= c11;
      x = __builtin_amdgcn_mfma_f32_16x16x32_f16(m2, q1, x, 0, 0, 0);
      x = __builtin_amdgcn_mfma_f32_16x16x32_f16(m1, q2, x, 0, 0, 0);
      x *= c11;
      f32x4 r = __builtin_amdgcn_mfma_f32_16x16x32_f16(m1, q1, x, 0, 0, 0);
#pragma unroll
      for (int j = 0; j < 4; ++j) {
        float v = fmaxf(r[j], 0.f) * et;
        if (v > th) {
          int p = atomicAdd(&cnt, 1);
          candk[p] = ((u32)l15 << 12) | (u32)(Tl * 16 + g * 4 + j);
          candv[p] = v;
        }
      }
    }
    __syncthreads();
    const int C = cnt;
    for (int c = tid; c < C; c += 256) {
      const u32 e = candk[c];
      const int r = (int)(e >> 12);
      const int f = seg * SEGW + (int)(e & 4095u);
      const float val = candv[c];
      const u32 wb = tf_xorbits(km0, km1, (u32)((t0 + r) * IJ + f));
      const float gmb = gumbel_from_bits(wb);
      const float v = logf((expf(val - mrow[r]) / srow[r]) / nv + 1e-20f) + gmb;
      const u64 key = ((u64)fkey(v) << 32) | (u64)(0xFFFFFFFFu - (u32)f);
      atomicMax(&best[r], key);
    }
    __syncthreads();
    if (tid == 0) cnt = 0;
    __syncthreads();
  }
  if (tid < 16) {
    const u64 k = best[tid];
    segv[(size_t)(t0 + tid) * NSEG + seg] = fkey_inv((u32)(k >> 32));
    segi[(size_t)(t0 + tid) * NSEG + seg] =
        (int)(0xFFFFFFFFu - (u32)(k & 0xFFFFFFFFu));
  }
}

__global__ void cat_reduce_kernel(const float* __restrict__ segv,
                                  const int* __restrict__ segi,
                                  int* __restrict__ m_flat) {
  const int idx = blockIdx.x * 256 + threadIdx.x;  // 0..1023 = b*512 + t
  if (idx >= NT) return;
  float bv = -1e30f;
  int bi = IJ;
#pragma unroll
  for (int s = 0; s < NSEG; ++s) {
    float v = segv[idx * NSEG + s];
    int i = segi[idx * NSEG + s];
    if (v > bv || (v == bv && i < bi)) { bv = v; bi = i; }
  }
  m_flat[idx] = bi;
}

// ---------------- pose hypotheses (R, t) -----------------------------------
__global__ void pose_kernel(const float* __restrict__ q_xy,
                            const int* __restrict__ n_idx,
                            const int* __restrict__ m_flat,
                            float4* __restrict__ poses) {
  const int idx = blockIdx.x * 256 + threadIdx.x;  // 0..511
  if (idx >= NB * KP) return;
  const int b = idx >> 8, k = idx & 255;
  const int t0 = b * 512 + 2 * k, t1 = t0 + 1;
  const int na = n_idx[t0], nb = n_idx[t1];
  const float2 q0 = ((const float2*)q_xy)[(size_t)b * NQ + na];
  const float2 q1 = ((const float2*)q_xy)[(size_t)b * NQ + nb];
  const int ma = m_flat[t0], mb = m_flat[t1];
  const float m0x = ((float)(ma >> 7) + 0.5f) * 0.5f;
  const float m0y = ((float)(ma & 127) + 0.5f) * 0.5f;
  const float m1x = ((float)(mb >> 7) + 0.5f) * 0.5f;
  const float m1y = ((float)(mb & 127) + 0.5f) * 0.5f;
  const float dqx = q1.x - q0.x, dqy = q1.y - q0.y;
  const float dmx = m1x - m0x, dmy = m1y - m0y;
  const float theta = atan2f(dmy, dmx) - atan2f(dqy, dqx);
  const float c = cosf(theta), s = sinf(theta);
  const float tx = m0x - (c * q0.x - s * q0.y);
  const float ty = m0y - (s * q0.x + c * q0.y);
  poses[idx] = make_float4(c, s, tx, ty);
}

// ---------------- score every pose: recompute sim on the fly ---------------
__global__ __launch_bounds__(256) void score_kernel(
    const float* __restrict__ f_q, const float* __restrict__ f_map,
    const float* __restrict__ q_xy, const void* __restrict__ valid_q,
    const void* __restrict__ valid_map, const float* __restrict__ num_valid,
    const float* __restrict__ temp, const float4* __restrict__ poses,
    const int* __restrict__ bool_is32, float* __restrict__ out) {
  __shared__ float sred[256];
  const int idx = blockIdx.x;  // b*256 + k
  const int tid = threadIdx.x;
  const int b = idx >> 8;
  const int is32 = bool_is32[0];
  const float4 P = poses[idx];
  const float et = expf(temp[0]);
  float acc = 0.f;
  for (int n = tid; n < NQ; n += 256) {
    float2 q = ((const float2*)q_xy)[(size_t)b * NQ + n];
    float px = P.x * q.x - P.y * q.y + P.z;
    float py = P.y * q.x + P.x * q.y + P.w;
    int ii = (int)floorf(px * 2.0f);  // / CELL (=0.5) is exact *2
    int jj = (int)floorf(py * 2.0f);
    bool inb = (ii >= 0) & (ii < 128) & (jj >= 0) & (jj < 128);
    int ic = min(max(ii, 0), 127), jc = min(max(jj, 0), 127);
    int flat = (ic << 7) + jc;
    bool msk = read_bool(valid_q, b * NQ + n, is32) && inb &&
               read_bool(valid_map, b * IJ + flat, is32);
    if (msk) {
      const float4* A = (const float4*)(f_q + ((size_t)b * NQ + n) * 32);
      const float4* Bm = (const float4*)(f_map + ((size_t)b * IJ + flat) * 32);
      float4 s4 = {0.f, 0.f, 0.f, 0.f};
#pragma unroll
      for (int r = 0; r < 8; ++r) {
        float4 a = A[r], bb = Bm[r];
        s4.x = fmaf(a.x, bb.x, s4.x);
        s4.y = fmaf(a.y, bb.y, s4.y);
        s4.z = fmaf(a.z, bb.z, s4.z);
        s4.w = fmaf(a.w, bb.w, s4.w);
      }
      float dot = (s4.x + s4.y) + (s4.z + s4.w);
      acc += fmaxf(dot, 0.f) * et;
    }
  }
  sred[tid] = acc;
  __syncthreads();
  for (int off = 128; off > 0; off >>= 1) {
    if (tid < off) sred[tid] += sred[tid + off];
    __syncthreads();
  }
  if (tid == 0) out[idx] = sred[0] / num_valid[b];
}

// ---------------------------------------------------------------------------
extern "C" void kernel_launch(void* const* d_in, const int* in_sizes, int n_in,
                              void* d_out, int out_size, void* d_ws,
                              size_t ws_size, hipStream_t stream) {
  const float* f_q = (const float*)d_in[0];
  const float* f_map = (const float*)d_in[1];
  const float* q_xy = (const float*)d_in[2];
  const float* temp = (const float*)d_in[3];
  const void* valid_q = d_in[4];
  const void* valid_map = d_in[5];
  const int* seedp = (const int*)d_in[6];
  float* out = (float*)d_out;

  char* ws = (char*)d_ws;
  _Float16* ms1 = (_Float16*)(ws + 0);            // 2 MB
  _Float16* ms2 = (_Float16*)(ws + 2097152);      // 2 MB
  _Float16* qs1 = (_Float16*)(ws + 4194304);      // 128 KB
  _Float16* qs2 = (_Float16*)(ws + 4325376);      // 128 KB
  float* tmax = (float*)(ws + 4456448);           // 4 KB
  float* tsum = (float*)(ws + 4460544);           // 4 KB
  float* rowsum_part = (float*)(ws + 4464640);    // 256 KB
  float* num_valid = (float*)(ws + 4726784);      // 64 B
  int* n_idx = (int*)(ws + 4726848);              // 4 KB
  int* m_flat = (int*)(ws + 4730944);             // 4 KB
  float4* poses = (float4*)(ws + 4735040);        // 8 KB
  int* bool_is32 = (int*)(ws + 4743232);          // 64 B
  float* segv = (float*)(ws + 4743296);           // 64 KB
  int* segi = (int*)(ws + 4808832);               // 64 KB

  setup_kernel<<<552, 256, 0, stream>>>(valid_q, seedp, f_q, f_map, tmax,
                                        num_valid, n_idx, bool_is32, ms1, ms2,
                                        qs1, qs2);
  stats_kernel<<<dim3(64, 16), 256, 0, stream>>>(ms1, ms2, qs1, qs2, n_idx,
                                                 temp, tmax, rowsum_part);
  sumexp_reduce_kernel<<<4, 256, 0, stream>>>(rowsum_part, tmax, tsum);
  select_kernel<<<dim3(NSEG, 64), 256, 0, stream>>>(
      ms1, ms2, qs1, qs2, n_idx, temp, tmax, tsum, num_valid, seedp, segv,
      segi);
  cat_reduce_kernel<<<4, 256, 0, stream>>>(segv, segi, m_flat);
  pose_kernel<<<2, 256, 0, stream>>>(q_xy, n_idx, m_flat, poses);
  score_kernel<<<NB * KP, 256, 0, stream>>>(f_q, f_map, q_xy, valid_q,
                                            valid_map, num_valid, temp, poses,
                                            bool_is32, out);
}

// Round 3
// 138.523 us; speedup vs baseline: 1.2027x; 1.0462x over previous
//
#include <hip/hip_runtime.h>
#include <stdint.h>

typedef unsigned int u32;
typedef unsigned long long u64;
typedef _Float16 f16x8 __attribute__((ext_vector_type(8)));
typedef float f32x4 __attribute__((ext_vector_type(4)));

#define IJ 16384
#define NQ 1024
#define NB 2
#define KP 256
#define NSEG 16
#define SEGW 1024  // IJ / NSEG
#define NT 1024    // sampled rows (2 batches x 512)

// ---------------- Threefry-2x32 (JAX-compatible, 20 rounds) ----------------
__device__ __forceinline__ void tf2x32(u32 k0, u32 k1, u32& x0, u32& x1) {
  u32 kx = k0 ^ k1 ^ 0x1BD11BDAu;
#define TFR(r) { x0 += x1; x1 = (x1 << (r)) | (x1 >> (32 - (r))); x1 ^= x0; }
  x0 += k0; x1 += k1;
  TFR(13) TFR(15) TFR(26) TFR(6)
  x0 += k1; x1 += kx + 1u;
  TFR(17) TFR(29) TFR(16) TFR(24)
  x0 += kx; x1 += k0 + 2u;
  TFR(13) TFR(15) TFR(26) TFR(6)
  x0 += k0; x1 += k1 + 3u;
  TFR(17) TFR(29) TFR(16) TFR(24)
  x0 += k1; x1 += kx + 4u;
  TFR(13) TFR(15) TFR(26) TFR(6)
  x0 += kx; x1 += k0 + 5u;
#undef TFR
}

__device__ __forceinline__ void tf_subkey(u32 k0, u32 k1, u32 i, u32& s0, u32& s1) {
  u32 x0 = 0u, x1 = i;
  tf2x32(k0, k1, x0, x1);
  s0 = x0; s1 = x1;
}

__device__ __forceinline__ u32 tf_xorbits(u32 k0, u32 k1, u32 i) {
  u32 x0 = 0u, x1 = i;
  tf2x32(k0, k1, x0, x1);
  return x0 ^ x1;
}

__device__ __forceinline__ void derive_keys(int seed, u32& kq0, u32& kq1,
                                            u32& km0, u32& km1) {
  u32 k0 = 0u;
  u32 k1 = (u32)seed;
  tf_subkey(k0, k1, 0u, kq0, kq1);
  tf_subkey(k0, k1, 1u, km0, km1);
}

// n_idx[s] = random_bits(k2)[s] & 1023, k2 = split(kq)[1]
__device__ __forceinline__ int derive_n(int seed, u32 s) {
  u32 kq0, kq1, km0, km1;
  derive_keys(seed, kq0, kq1, km0, km1);
  u32 l0, l1;
  tf_subkey(kq0, kq1, 1u, l0, l1);
  return (int)(tf_xorbits(l0, l1, s) & 1023u);
}

__device__ __forceinline__ float gumbel_from_bits(u32 w) {
  const float tiny = 1.17549435e-38f;
  float fl = __uint_as_float((w >> 9) | 0x3f800000u) - 1.0f;
  float u = fl * (1.0f - tiny) + tiny;
  u = fmaxf(tiny, u);
  return -logf(-logf(u));
}

__device__ __forceinline__ bool read_bool(const void* p, int idx, int is32) {
  return is32 ? (((const int*)p)[idx] != 0)
              : (((const unsigned char*)p)[idx] != 0);
}

// monotone float<->u32 key (finite, non-NaN inputs)
__device__ __forceinline__ u32 fkey(float x) {
  u32 b = __float_as_uint(x);
  return b ^ ((b & 0x80000000u) ? 0xFFFFFFFFu : 0x80000000u);
}

// f32 -> (f16 hi, f16 lo*2^11) split, in-register (identical in both passes)
__device__ __forceinline__ void load_split(const float* __restrict__ src,
                                           f16x8& h1, f16x8& h2) {
  float4 a = *(const float4*)src;
  float4 b = *(const float4*)(src + 16);
  float x[8] = {a.x, a.y, a.z, a.w, b.x, b.y, b.z, b.w};
#pragma unroll
  for (int e = 0; e < 8; ++e) {
    _Float16 hi = (_Float16)x[e];
    h1[e] = hi;
    h2[e] = (_Float16)((x[e] - (float)hi) * 2048.0f);
  }
}

// fp32-emulated 16x16x32 via 4-MFMA Horner (error ~2^-21 per product)
__device__ __forceinline__ f32x4 emul_mfma(f16x8 m1, f16x8 m2, f16x8 q1,
                                           f16x8 q2) {
  const f32x4 zero4 = {0.f, 0.f, 0.f, 0.f};
  const float c11 = 4.8828125e-4f;  // 2^-11
  f32x4 x = __builtin_amdgcn_mfma_f32_16x16x32_f16(m2, q2, zero4, 0, 0, 0);
  x *= c11;
  x = __builtin_amdgcn_mfma_f32_16x16x32_f16(m2, q1, x, 0, 0, 0);
  x = __builtin_amdgcn_mfma_f32_16x16x32_f16(m1, q2, x, 0, 0, 0);
  x *= c11;
  return __builtin_amdgcn_mfma_f32_16x16x32_f16(m1, q1, x, 0, 0, 0);
}

// ---------------- K1: per-sampled-row chunk max + chunk sumexp -------------
// grid (64 ij-chunks, 16 row-groups); wave w owns rows [by*64+16w, +16).
// Plain stores (no init dependency); block (0,0) also does side jobs:
// best[] init, bool-width detect, num_valid.
__global__ __launch_bounds__(256) void stats_kernel(
    const float* __restrict__ f_q, const float* __restrict__ f_map,
    const float* __restrict__ temp, const void* __restrict__ valid_q,
    const int* __restrict__ seedp, float* __restrict__ chunkmax,
    float* __restrict__ rowsum_part, u64* __restrict__ best,
    float* __restrict__ num_valid, int* __restrict__ bool_is32) {
  __shared__ int sred[256];
  __shared__ int is32_s;
  const int bx = blockIdx.x;  // 256-ij chunk
  const int by = blockIdx.y;  // 64-row group
  const int tid = threadIdx.x;
  const int w = tid >> 6, l = tid & 63, l15 = l & 15, g = l >> 4;
  const int b = by >> 3;
  const int tp = by * 64 + w * 16 + l15;
  const int n = derive_n(seedp[0], (u32)tp);
  f16x8 q1, q2;
  load_split(f_q + ((size_t)b * NQ + n) * 32 + g * 4, q1, q2);
  const float et = expf(temp[0]);
  float rm = 0.f, se = 0.f;
#pragma unroll
  for (int T = 0; T < 16; ++T) {
    f16x8 m1, m2;
    load_split(f_map + ((size_t)b * IJ + (bx * 16 + T) * 16 + l15) * 32 + g * 4,
               m1, m2);
    f32x4 r = emul_mfma(m1, m2, q1, q2);
#pragma unroll
    for (int j = 0; j < 4; ++j) {
      float v = fmaxf(r[j], 0.f) * et;
      rm = fmaxf(rm, v);
      se += __expf(v);  // s only enters v as per-row log-shift: fast exp safe
    }
  }
  // deterministic reduce over the 4 lanes (g=0..3) holding the same row
  se += __shfl_xor(se, 16, 64);
  rm = fmaxf(rm, __shfl_xor(rm, 16, 64));
  se += __shfl_xor(se, 32, 64);
  rm = fmaxf(rm, __shfl_xor(rm, 32, 64));
  if (g == 0) {
    chunkmax[(size_t)tp * 64 + bx] = rm;
    rowsum_part[(size_t)tp * 64 + bx] = se;
  }
  if (bx == 0 && by == 0) {  // uniform per block: side jobs
    __syncthreads();
    for (int i = tid; i < NT; i += 256) best[i] = 0ull;  // fkey(-inf) floor
    const unsigned char* vb = (const unsigned char*)valid_q;
    int ones = 0;
    for (int i = tid; i < 2048; i += 256) ones += (vb[i] == 1) ? 1 : 0;
    sred[tid] = ones;
    __syncthreads();
    for (int off = 128; off > 0; off >>= 1) {
      if (tid < off) sred[tid] += sred[tid + off];
      __syncthreads();
    }
    if (tid == 0) {
      is32_s = (sred[0] < 1152) ? 1 : 0;
      bool_is32[0] = is32_s;
    }
    __syncthreads();
    const int is32 = is32_s;
    for (int bb = 0; bb < 2; ++bb) {
      int acc = 0;
      for (int i = tid; i < NQ; i += 256)
        acc += read_bool(valid_q, bb * NQ + i, is32) ? 1 : 0;
      sred[tid] = acc;
      __syncthreads();
      for (int off = 128; off > 0; off >>= 1) {
        if (tid < off) sred[tid] += sred[tid + off];
        __syncthreads();
      }
      if (tid == 0) {
        float nv = (float)sred[0];
        num_valid[bb] = nv < 1.f ? 1.f : nv;
      }
      __syncthreads();
    }
  }
}

// ---------------- K2: recompute + categorical argmax -----------------------
// Block = 16 sampled rows x SEGW ij. Recomputes sim bitwise == K1 (same
// loads, same split, same Horner). Per-block mrow/srow reduced in fixed order
// (bitwise == old sumexp_reduce). Candidates (val > m-22; winner bound
// m-21.11) compacted to LDS; exact R7 v; (max v, min f) via packed u64
// atomicMax (LDS then one global per row).
__global__ __launch_bounds__(256) void select_kernel(
    const float* __restrict__ f_q, const float* __restrict__ f_map,
    const float* __restrict__ temp, const float* __restrict__ chunkmax,
    const float* __restrict__ rowsum_part, const float* __restrict__ num_valid,
    const int* __restrict__ seedp, u64* __restrict__ best) {
  __shared__ float mrow[16], srow[16];
  __shared__ u64 lbest[16];
  __shared__ int cnt;
  __shared__ u32 candk[4096];
  __shared__ float candv[4096];
  const int seg = blockIdx.x;  // 0..15
  const int tg = blockIdx.y;   // 0..63
  const int tid = threadIdx.x;
  const int w = tid >> 6, l = tid & 63, l15 = l & 15, g = l >> 4;
  const int b = tg >> 5;
  const int t0 = tg * 16;
  u32 kq0, kq1, km0, km1;
  derive_keys(seedp[0], kq0, kq1, km0, km1);
  if (tid < 16) {
    const float* cm = chunkmax + (size_t)(t0 + tid) * 64;
    const float* rp = rowsum_part + (size_t)(t0 + tid) * 64;
    float m = 0.f;
#pragma unroll
    for (int c = 0; c < 64; ++c) m = fmaxf(m, cm[c]);
    float s = 0.f;
#pragma unroll
    for (int c = 0; c < 64; ++c) s += rp[c];  // fixed order: deterministic
    mrow[tid] = m;
    srow[tid] = s * expf(-m);
    lbest[tid] = 0ull;
  }
  if (tid == 0) cnt = 0;
  const int n = derive_n(seedp[0], (u32)(t0 + l15));
  f16x8 q1, q2;
  load_split(f_q + ((size_t)b * NQ + n) * 32 + g * 4, q1, q2);
  const float et = expf(temp[0]);
  const float nv = num_valid[b];
  __syncthreads();
  const float th = mrow[l15] - 22.0f;

  for (int sc = 0; sc < 4; ++sc) {
#pragma unroll
    for (int i = 0; i < 4; ++i) {
      const int Tl = sc * 16 + w * 4 + i;  // tile within seg: 0..63
      f16x8 m1, m2;
      load_split(
          f_map + ((size_t)b * IJ + seg * SEGW + Tl * 16 + l15) * 32 + g * 4,
          m1, m2);
      f32x4 r = emul_mfma(m1, m2, q1, q2);
#pragma unroll
      for (int j = 0; j < 4; ++j) {
        float v = fmaxf(r[j], 0.f) * et;
        if (v > th) {
          int p = atomicAdd(&cnt, 1);
          candk[p] = ((u32)l15 << 12) | (u32)(Tl * 16 + g * 4 + j);
          candv[p] = v;
        }
      }
    }
    __syncthreads();
    const int C = cnt;
    for (int c = tid; c < C; c += 256) {
      const u32 e = candk[c];
      const int r = (int)(e >> 12);
      const int f = seg * SEGW + (int)(e & 4095u);
      const float val = candv[c];
      const u32 wb = tf_xorbits(km0, km1, (u32)((t0 + r) * IJ + f));
      const float gmb = gumbel_from_bits(wb);
      const float v = logf((expf(val - mrow[r]) / srow[r]) / nv + 1e-20f) + gmb;
      const u64 key = ((u64)fkey(v) << 32) | (u64)(0xFFFFFFFFu - (u32)f);
      atomicMax(&lbest[r], key);
    }
    __syncthreads();
    if (tid == 0) cnt = 0;
    __syncthreads();
  }
  if (tid < 16) atomicMax(&best[t0 + tid], lbest[tid]);
}

// ---------------- K3: pose (inline) + score, recompute sim on the fly ------
__global__ __launch_bounds__(256) void score_kernel(
    const float* __restrict__ f_q, const float* __restrict__ f_map,
    const float* __restrict__ q_xy, const void* __restrict__ valid_q,
    const void* __restrict__ valid_map, const float* __restrict__ num_valid,
    const float* __restrict__ temp, const u64* __restrict__ best,
    const int* __restrict__ seedp, const int* __restrict__ bool_is32,
    float* __restrict__ out) {
  __shared__ float sred[256];
  __shared__ float4 Psh;
  const int idx = blockIdx.x;  // b*256 + k
  const int tid = threadIdx.x;
  const int b = idx >> 8, k = idx & 255;
  if (tid == 0) {
    const int t0 = b * 512 + 2 * k, t1 = t0 + 1;
    const int na = derive_n(seedp[0], (u32)t0);
    const int nb = derive_n(seedp[0], (u32)t1);
    const float2 q0 = ((const float2*)q_xy)[(size_t)b * NQ + na];
    const float2 q1 = ((const float2*)q_xy)[(size_t)b * NQ + nb];
    const int ma = (int)(0xFFFFFFFFu - (u32)(best[t0] & 0xFFFFFFFFu));
    const int mb = (int)(0xFFFFFFFFu - (u32)(best[t1] & 0xFFFFFFFFu));
    const float m0x = ((float)(ma >> 7) + 0.5f) * 0.5f;
    const float m0y = ((float)(ma & 127) + 0.5f) * 0.5f;
    const float m1x = ((float)(mb >> 7) + 0.5f) * 0.5f;
    const float m1y = ((float)(mb & 127) + 0.5f) * 0.5f;
    const float dqx = q1.x - q0.x, dqy = q1.y - q0.y;
    const float dmx = m1x - m0x, dmy = m1y - m0y;
    const float theta = atan2f(dmy, dmx) - atan2f(dqy, dqx);
    const float c = cosf(theta), s = sinf(theta);
    const float tx = m0x - (c * q0.x - s * q0.y);
    const float ty = m0y - (s * q0.x + c * q0.y);
    Psh = make_float4(c, s, tx, ty);
  }
  __syncthreads();
  const float4 P = Psh;
  const int is32 = bool_is32[0];
  const float et = expf(temp[0]);
  float acc = 0.f;
  for (int n = tid; n < NQ; n += 256) {
    float2 q = ((const float2*)q_xy)[(size_t)b * NQ + n];
    float px = P.x * q.x - P.y * q.y + P.z;
    float py = P.y * q.x + P.x * q.y + P.w;
    int ii = (int)floorf(px * 2.0f);  // / CELL (=0.5) is exact *2
    int jj = (int)floorf(py * 2.0f);
    bool inb = (ii >= 0) & (ii < 128) & (jj >= 0) & (jj < 128);
    int ic = min(max(ii, 0), 127), jc = min(max(jj, 0), 127);
    int flat = (ic << 7) + jc;
    bool msk = read_bool(valid_q, b * NQ + n, is32) && inb &&
               read_bool(valid_map, b * IJ + flat, is32);
    if (msk) {
      const float4* A = (const float4*)(f_q + ((size_t)b * NQ + n) * 32);
      const float4* Bm = (const float4*)(f_map + ((size_t)b * IJ + flat) * 32);
      float4 s4 = {0.f, 0.f, 0.f, 0.f};
#pragma unroll
      for (int r = 0; r < 8; ++r) {
        float4 a = A[r], bb = Bm[r];
        s4.x = fmaf(a.x, bb.x, s4.x);
        s4.y = fmaf(a.y, bb.y, s4.y);
        s4.z = fmaf(a.z, bb.z, s4.z);
        s4.w = fmaf(a.w, bb.w, s4.w);
      }
      float dot = (s4.x + s4.y) + (s4.z + s4.w);
      acc += fmaxf(dot, 0.f) * et;
    }
  }
  sred[tid] = acc;
  __syncthreads();
  for (int off = 128; off > 0; off >>= 1) {
    if (tid < off) sred[tid] += sred[tid + off];
    __syncthreads();
  }
  if (tid == 0) out[idx] = sred[0] / num_valid[b];
}

// ---------------------------------------------------------------------------
extern "C" void kernel_launch(void* const* d_in, const int* in_sizes, int n_in,
                              void* d_out, int out_size, void* d_ws,
                              size_t ws_size, hipStream_t stream) {
  const float* f_q = (const float*)d_in[0];
  const float* f_map = (const float*)d_in[1];
  const float* q_xy = (const float*)d_in[2];
  const float* temp = (const float*)d_in[3];
  const void* valid_q = d_in[4];
  const void* valid_map = d_in[5];
  const int* seedp = (const int*)d_in[6];
  float* out = (float*)d_out;

  char* ws = (char*)d_ws;
  float* chunkmax = (float*)ws;                  // 1024*64*4 = 256 KB
  float* rowsum_part = (float*)(ws + 262144);    // 256 KB
  u64* best = (u64*)(ws + 524288);               // 8 KB
  float* num_valid = (float*)(ws + 532480);      // 8 B
  int* bool_is32 = (int*)(ws + 532544);          // 4 B

  stats_kernel<<<dim3(64, 16), 256, 0, stream>>>(
      f_q, f_map, temp, valid_q, seedp, chunkmax, rowsum_part, best, num_valid,
      bool_is32);
  select_kernel<<<dim3(NSEG, 64), 256, 0, stream>>>(
      f_q, f_map, temp, chunkmax, rowsum_part, num_valid, seedp, best);
  score_kernel<<<NB * KP, 256, 0, stream>>>(f_q, f_map, q_xy, valid_q,
                                            valid_map, num_valid, temp, best,
                                            seedp, bool_is32, out);
}